// Round 1
// baseline (1229.374 us; speedup 1.0000x reference)
//
#include <hip/hip_runtime.h>
#include <hip/hip_bf16.h>

// DynamicRouterMoE: N=8192 tokens, C=1024, Hdim=4096, E=16, top-2.
// Sparse formulation: only the 2 selected experts per token are computed.
// Router in fp64 (top-k tie safety); expert FFN GEMMs in bf16 MFMA.

typedef __attribute__((ext_vector_type(4))) float f32x4;
typedef __attribute__((ext_vector_type(8))) __bf16 bf16x8;
typedef __attribute__((ext_vector_type(8))) unsigned short u16x8;

#define NEXP 16
#define CAP  2048   // max tokens per expert tracked (E[n_e]=1024, sigma~31)
#define CDIM 1024
#define HDIM 4096
#define BM 128
#define BN 128
#define BK 64

// fp32 -> bf16 RNE via plain cast; compiler emits v_cvt_pk_bf16_f32 pairs.
__device__ __forceinline__ unsigned short f2bf(float f) {
  return __builtin_bit_cast(unsigned short, (__bf16)f);
}

// LDS tile: [row][BK] bf16, 128B rows. XOR-swizzle 16B quads so both the
// transposed staging writes and the b128 fragment reads are conflict-free
// (8 lanes per 4-bank span == the 16B/lane LDS bandwidth floor).
__device__ __forceinline__ int swz(int row, int b) {
  return row * (BK * 2) + (b ^ (((row >> 1) & 7) << 4));
}

// ---------------- router: logits(fp64) -> top2 -> softmax -> lists ----------
__global__ __launch_bounds__(64) void router_kernel(
    const float* __restrict__ x, const float* __restrict__ wr,
    float* __restrict__ pair_w, int* __restrict__ counts,
    int* __restrict__ lists)
{
  const int n = blockIdx.x;
  const int l = threadIdx.x;
  const float* xrow = x + (size_t)n * CDIM;
  double acc[NEXP];
#pragma unroll
  for (int e = 0; e < NEXP; e++) acc[e] = 0.0;
  for (int it = 0; it < CDIM / 64; it++) {
    const int c = l + it * 64;
    const double xv = (double)xrow[c];
    const float* w = wr + c * NEXP;
#pragma unroll
    for (int e = 0; e < NEXP; e++) acc[e] += xv * (double)w[e];
  }
#pragma unroll
  for (int e = 0; e < NEXP; e++) {
    double v = acc[e];
    for (int off = 32; off > 0; off >>= 1) v += __shfl_xor(v, off, 64);
    acc[e] = v;
  }
  if (l == 0) {
    int e0 = 0; double b0 = acc[0];
    for (int e = 1; e < NEXP; e++) if (acc[e] > b0) { b0 = acc[e]; e0 = e; }
    int e1 = -1; double b1v = -1e300;
    for (int e = 0; e < NEXP; e++) {
      if (e == e0) continue;
      if (acc[e] > b1v) { b1v = acc[e]; e1 = e; }
    }
    const double d = exp(b1v - b0);
    pair_w[2 * n]     = (float)(1.0 / (1.0 + d));
    pair_w[2 * n + 1] = (float)(d / (1.0 + d));
    int p0 = atomicAdd(&counts[e0], 1);
    if (p0 < CAP) lists[e0 * CAP + p0] = 2 * n;
    int p1 = atomicAdd(&counts[e1], 1);
    if (p1 < CAP) lists[e1 * CAP + p1] = 2 * n + 1;
  }
}

// ---------------- GEMM1: H[pair] = relu(x[token] @ w1[e] + b1[e]) -----------
__global__ __launch_bounds__(256) void gemm1_kernel(
    const float* __restrict__ x, const float* __restrict__ w1,
    const float* __restrict__ b1, const int* __restrict__ counts,
    const int* __restrict__ lists, unsigned short* __restrict__ Hb,
    int e_base, int h_by_pair)
{
  const int e = e_base + blockIdx.z;
  int cnt = counts[e]; if (cnt > CAP) cnt = CAP;
  const int m0 = blockIdx.y * BM;
  if (m0 >= cnt) return;
  const int n0 = blockIdx.x * BN;
  const int* list = lists + e * CAP;
  const float* W = w1 + (size_t)e * CDIM * HDIM;

  __shared__ __align__(16) unsigned short As[BM * BK];
  __shared__ __align__(16) unsigned short Bs[BN * BK];

  const int t = threadIdx.x;
  // A staging: thread -> (row, 32-col half) of the 128x64 A tile
  const int a_row = t >> 1, a_half = t & 1;
  int a_idx = m0 + a_row; if (a_idx > cnt - 1) a_idx = cnt - 1;
  const float* a_src = x + (size_t)(list[a_idx] >> 1) * CDIM + a_half * 32;
  // B staging: thread -> 2 adjacent n-columns x 8 k (x2 iterations)
  const int b_np = t & 63, b_kg = t >> 6;

  const int wid = t >> 6, lane = t & 63;
  const int wm = (wid >> 1) * 64, wn = (wid & 1) * 64;
  const int lrow = lane & 15, lgrp = lane >> 4;

  f32x4 acc[4][4] = {};

  for (int kt = 0; kt < CDIM; kt += BK) {
    {  // stage A (gather rows of x, fp32 -> bf16)
      const float* s = a_src + kt;
      u16x8 cv[4];
#pragma unroll
      for (int q = 0; q < 4; q++) {
        float4 v0 = *(const float4*)(s + q * 8);
        float4 v1 = *(const float4*)(s + q * 8 + 4);
        cv[q][0] = f2bf(v0.x); cv[q][1] = f2bf(v0.y);
        cv[q][2] = f2bf(v0.z); cv[q][3] = f2bf(v0.w);
        cv[q][4] = f2bf(v1.x); cv[q][5] = f2bf(v1.y);
        cv[q][6] = f2bf(v1.z); cv[q][7] = f2bf(v1.w);
      }
#pragma unroll
      for (int q = 0; q < 4; q++)
        *(u16x8*)((char*)As + swz(a_row, (a_half * 32 + q * 8) * 2)) = cv[q];
    }
    {  // stage B transposed: Bs[n][k], coalesced dword2 loads per k-row
#pragma unroll
      for (int it = 0; it < 2; it++) {
        const int k0 = (b_kg + 4 * it) * 8;
        u16x8 c0, c1;
#pragma unroll
        for (int j = 0; j < 8; j++) {
          float2 v = *(const float2*)(W + (size_t)(kt + k0 + j) * HDIM + n0 + 2 * b_np);
          c0[j] = f2bf(v.x); c1[j] = f2bf(v.y);
        }
        *(u16x8*)((char*)Bs + swz(2 * b_np,     k0 * 2)) = c0;
        *(u16x8*)((char*)Bs + swz(2 * b_np + 1, k0 * 2)) = c1;
      }
    }
    __syncthreads();
#pragma unroll
    for (int kk = 0; kk < 2; kk++) {
      bf16x8 af[4], bfr[4];
      const int kb = (kk * 32 + lgrp * 8) * 2;
#pragma unroll
      for (int i = 0; i < 4; i++)
        af[i] = *(const bf16x8*)((const char*)As + swz(wm + i * 16 + lrow, kb));
#pragma unroll
      for (int j = 0; j < 4; j++)
        bfr[j] = *(const bf16x8*)((const char*)Bs + swz(wn + j * 16 + lrow, kb));
#pragma unroll
      for (int i = 0; i < 4; i++)
#pragma unroll
        for (int j = 0; j < 4; j++)
          acc[i][j] = __builtin_amdgcn_mfma_f32_16x16x32_bf16(af[i], bfr[j], acc[i][j], 0, 0, 0);
    }
    __syncthreads();
  }

  // epilogue: +b1, relu, bf16 -> Hb
  int hrow[4][4]; bool valid[4][4];
#pragma unroll
  for (int i = 0; i < 4; i++)
#pragma unroll
    for (int r = 0; r < 4; r++) {
      const int mi = m0 + wm + i * 16 + lgrp * 4 + r;
      valid[i][r] = (mi < cnt);
      const int idx = valid[i][r] ? mi : (cnt - 1);
      hrow[i][r] = h_by_pair ? list[idx] : idx;
    }
#pragma unroll
  for (int j = 0; j < 4; j++) {
    const int col = n0 + wn + j * 16 + lrow;
    const float bias = b1[e * HDIM + col];
#pragma unroll
    for (int i = 0; i < 4; i++)
#pragma unroll
      for (int r = 0; r < 4; r++)
        if (valid[i][r]) {
          float h = acc[i][j][r] + bias;
          h = h > 0.f ? h : 0.f;
          Hb[(size_t)hrow[i][r] * HDIM + col] = f2bf(h);
        }
  }
}

// ---------------- GEMM2: out[token] += w_pair * (H[pair] @ w2[e] + b2[e]) ---
__global__ __launch_bounds__(256) void gemm2_kernel(
    const unsigned short* __restrict__ Hb, const float* __restrict__ w2,
    const float* __restrict__ b2, const float* __restrict__ pair_w,
    const int* __restrict__ counts, const int* __restrict__ lists,
    float* __restrict__ out, int e_base, int h_by_pair)
{
  const int e = e_base + blockIdx.z;
  int cnt = counts[e]; if (cnt > CAP) cnt = CAP;
  const int m0 = blockIdx.y * BM;
  if (m0 >= cnt) return;
  const int n0 = blockIdx.x * BN;
  const int* list = lists + e * CAP;
  const float* W = w2 + (size_t)e * HDIM * CDIM;

  __shared__ __align__(16) unsigned short As[BM * BK];
  __shared__ __align__(16) unsigned short Bs[BN * BK];

  const int t = threadIdx.x;
  const int a_row = t >> 1, a_half = t & 1;
  int a_idx = m0 + a_row; if (a_idx > cnt - 1) a_idx = cnt - 1;
  const unsigned short* a_src =
      Hb + (size_t)(h_by_pair ? list[a_idx] : a_idx) * HDIM + a_half * 32;

  const int b_np = t & 63, b_kg = t >> 6;
  const int wid = t >> 6, lane = t & 63;
  const int wm = (wid >> 1) * 64, wn = (wid & 1) * 64;
  const int lrow = lane & 15, lgrp = lane >> 4;

  f32x4 acc[4][4] = {};

  for (int kt = 0; kt < HDIM; kt += BK) {
    {  // stage A: already bf16, straight 16B copies
      const unsigned short* s = a_src + kt;
#pragma unroll
      for (int q = 0; q < 4; q++) {
        u16x8 v = *(const u16x8*)(s + q * 8);
        *(u16x8*)((char*)As + swz(a_row, (a_half * 32 + q * 8) * 2)) = v;
      }
    }
    {  // stage B transposed (w2 fp32 -> bf16)
#pragma unroll
      for (int it = 0; it < 2; it++) {
        const int k0 = (b_kg + 4 * it) * 8;
        u16x8 c0, c1;
#pragma unroll
        for (int j = 0; j < 8; j++) {
          float2 v = *(const float2*)(W + (size_t)(kt + k0 + j) * CDIM + n0 + 2 * b_np);
          c0[j] = f2bf(v.x); c1[j] = f2bf(v.y);
        }
        *(u16x8*)((char*)Bs + swz(2 * b_np,     k0 * 2)) = c0;
        *(u16x8*)((char*)Bs + swz(2 * b_np + 1, k0 * 2)) = c1;
      }
    }
    __syncthreads();
#pragma unroll
    for (int kk = 0; kk < 2; kk++) {
      bf16x8 af[4], bfr[4];
      const int kb = (kk * 32 + lgrp * 8) * 2;
#pragma unroll
      for (int i = 0; i < 4; i++)
        af[i] = *(const bf16x8*)((const char*)As + swz(wm + i * 16 + lrow, kb));
#pragma unroll
      for (int j = 0; j < 4; j++)
        bfr[j] = *(const bf16x8*)((const char*)Bs + swz(wn + j * 16 + lrow, kb));
#pragma unroll
      for (int i = 0; i < 4; i++)
#pragma unroll
        for (int j = 0; j < 4; j++)
          acc[i][j] = __builtin_amdgcn_mfma_f32_16x16x32_bf16(af[i], bfr[j], acc[i][j], 0, 0, 0);
    }
    __syncthreads();
  }

  // epilogue: +b2, scale by routing weight, accumulate into out.
  // Exactly 2 atomic adds per output element (commutative) -> deterministic.
  float wgt[4][4]; int tok[4][4]; bool valid[4][4];
#pragma unroll
  for (int i = 0; i < 4; i++)
#pragma unroll
    for (int r = 0; r < 4; r++) {
      const int mi = m0 + wm + i * 16 + lgrp * 4 + r;
      valid[i][r] = (mi < cnt);
      const int idx = valid[i][r] ? mi : (cnt - 1);
      const int p = list[idx];
      wgt[i][r] = pair_w[p];
      tok[i][r] = p >> 1;
    }
#pragma unroll
  for (int j = 0; j < 4; j++) {
    const int col = n0 + wn + j * 16 + lrow;
    const float bias = b2[e * CDIM + col];
#pragma unroll
    for (int i = 0; i < 4; i++)
#pragma unroll
      for (int r = 0; r < 4; r++)
        if (valid[i][r])
          atomicAdd(out + (size_t)tok[i][r] * CDIM + col,
                    wgt[i][r] * (acc[i][j][r] + bias));
  }
}

extern "C" void kernel_launch(void* const* d_in, const int* in_sizes, int n_in,
                              void* d_out, int out_size, void* d_ws, size_t ws_size,
                              hipStream_t stream)
{
  const float* x  = (const float*)d_in[0];
  const float* wr = (const float*)d_in[1];
  const float* w1 = (const float*)d_in[2];
  const float* b1 = (const float*)d_in[3];
  const float* w2 = (const float*)d_in[4];
  const float* b2 = (const float*)d_in[5];
  float* out = (float*)d_out;

  const int N = in_sizes[0] / CDIM;  // 8192 tokens

  char* ws = (char*)d_ws;
  int* counts = (int*)ws;                                  // 16 ints
  int* lists  = (int*)(ws + 256);                          // 16*CAP ints
  float* pw   = (float*)(ws + 256 + NEXP * CAP * 4);       // 2N floats
  size_t Hoff = 256 + (size_t)NEXP * CAP * 4 + (size_t)2 * N * 4;
  Hoff = (Hoff + 255) & ~(size_t)255;
  unsigned short* Hb = (unsigned short*)(ws + Hoff);

  const size_t need_A = Hoff + (size_t)2 * N * HDIM * 2;   // ~134.5 MB
  const size_t need_B = Hoff + (size_t)CAP * HDIM * 2;     // ~17 MB

  hipMemsetAsync(d_ws, 0, 64, stream);                       // counts = 0
  hipMemsetAsync(d_out, 0, (size_t)out_size * 4, stream);    // out = 0

  router_kernel<<<N, 64, 0, stream>>>(x, wr, pw, counts, lists);

  if (ws_size >= need_A) {
    // all experts in one grid; H indexed by global pair id
    gemm1_kernel<<<dim3(HDIM / BN, CAP / BM, NEXP), 256, 0, stream>>>(
        x, w1, b1, counts, lists, Hb, 0, 1);
    gemm2_kernel<<<dim3(CDIM / BN, CAP / BM, NEXP), 256, 0, stream>>>(
        Hb, w2, b2, pw, counts, lists, out, 0, 1);
  } else if (ws_size >= need_B) {
    // fallback: per-expert sequential, H indexed by list position
    for (int e = 0; e < NEXP; e++) {
      gemm1_kernel<<<dim3(HDIM / BN, CAP / BM, 1), 256, 0, stream>>>(
          x, w1, b1, counts, lists, Hb, e, 0);
      gemm2_kernel<<<dim3(CDIM / BN, CAP / BM, 1), 256, 0, stream>>>(
          Hb, w2, b2, pw, counts, lists, out, e, 0);
    }
  }
}

// Round 2
// 1085.183 us; speedup vs baseline: 1.1329x; 1.1329x over previous
//
#include <hip/hip_runtime.h>
#include <hip/hip_bf16.h>

// DynamicRouterMoE: N=8192 tokens, C=1024, Hdim=4096, E=16, top-2.
// R1: pre-convert weights (transposed) + x to bf16, then m97-style GEMMs
// with global_load_lds(16B) staging + XOR-swizzled LDS (pre-swizzled source).

typedef __attribute__((ext_vector_type(4))) float f32x4;
typedef __attribute__((ext_vector_type(8))) __bf16 bf16x8;
typedef __attribute__((ext_vector_type(8))) unsigned short u16x8;

#define NEXP 16
#define CAP  2048
#define CDIM 1024
#define HDIM 4096
#define BM 128
#define BN 128
#define BK 64

__device__ __forceinline__ unsigned short f2bf(float f) {
  return __builtin_bit_cast(unsigned short, (__bf16)f);
}

// LDS tile [row][BK] bf16 (128B rows), 16B quads XOR-swizzled by row pair.
__device__ __forceinline__ int swz(int row, int b) {
  return row * (BK * 2) + (b ^ (((row >> 1) & 7) << 4));
}

typedef __attribute__((address_space(3))) void  lds_void;
typedef __attribute__((address_space(1))) const void gbl_void;
__device__ __forceinline__ void gload16(const void* g, void* l) {
  __builtin_amdgcn_global_load_lds((gbl_void*)g, (lds_void*)l, 16, 0, 0);
}

// ---------------- router: logits(fp64) -> top2 -> softmax -> lists ----------
__global__ __launch_bounds__(64) void router_kernel(
    const float* __restrict__ x, const float* __restrict__ wr,
    float* __restrict__ pair_w, int* __restrict__ counts,
    int* __restrict__ lists)
{
  const int n = blockIdx.x;
  const int l = threadIdx.x;
  const float* xrow = x + (size_t)n * CDIM;
  double acc[NEXP];
#pragma unroll
  for (int e = 0; e < NEXP; e++) acc[e] = 0.0;
  for (int it = 0; it < CDIM / 64; it++) {
    const int c = l + it * 64;
    const double xv = (double)xrow[c];
    const float* w = wr + c * NEXP;
#pragma unroll
    for (int e = 0; e < NEXP; e++) acc[e] += xv * (double)w[e];
  }
#pragma unroll
  for (int e = 0; e < NEXP; e++) {
    double v = acc[e];
    for (int off = 32; off > 0; off >>= 1) v += __shfl_xor(v, off, 64);
    acc[e] = v;
  }
  if (l == 0) {
    int e0 = 0; double b0 = acc[0];
    for (int e = 1; e < NEXP; e++) if (acc[e] > b0) { b0 = acc[e]; e0 = e; }
    int e1 = -1; double b1v = -1e300;
    for (int e = 0; e < NEXP; e++) {
      if (e == e0) continue;
      if (acc[e] > b1v) { b1v = acc[e]; e1 = e; }
    }
    const double d = exp(b1v - b0);
    pair_w[2 * n]     = (float)(1.0 / (1.0 + d));
    pair_w[2 * n + 1] = (float)(d / (1.0 + d));
    int p0 = atomicAdd(&counts[e0], 1);
    if (p0 < CAP) lists[e0 * CAP + p0] = 2 * n;
    int p1 = atomicAdd(&counts[e1], 1);
    if (p1 < CAP) lists[e1 * CAP + p1] = 2 * n + 1;
  }
}

// ---------------- convert x -> bf16 ----------------------------------------
__global__ __launch_bounds__(256) void cvt_x_kernel(
    const float* __restrict__ x, unsigned short* __restrict__ xb, int n8)
{
  const int i = blockIdx.x * 256 + threadIdx.x;
  if (i >= n8) return;
  float4 a = ((const float4*)x)[2 * i];
  float4 b = ((const float4*)x)[2 * i + 1];
  u16x8 v;
  v[0] = f2bf(a.x); v[1] = f2bf(a.y); v[2] = f2bf(a.z); v[3] = f2bf(a.w);
  v[4] = f2bf(b.x); v[5] = f2bf(b.y); v[6] = f2bf(b.z); v[7] = f2bf(b.w);
  ((u16x8*)xb)[i] = v;
}

// ------------- transpose+convert: src fp32 [K][Nn] -> dst bf16 [Nn][K] ------
__global__ __launch_bounds__(256) void transpose_cvt_kernel(
    const float* __restrict__ src, unsigned short* __restrict__ dst,
    int K, int Nn)
{
  __shared__ __align__(16) unsigned short tile[64][72];  // +8 pad: conflict-free
  const size_t eoff = (size_t)blockIdx.z * K * Nn;
  const float* S = src + eoff;
  unsigned short* D = dst + eoff;
  const int n0 = blockIdx.x * 64, k0 = blockIdx.y * 64;
  const int t = threadIdx.x;
  {
    const int nl = (t & 15) * 4, kr = t >> 4;   // 16 k-rows per pass
#pragma unroll
    for (int p = 0; p < 4; p++) {
      const int k = kr + p * 16;
      float4 v = *(const float4*)(S + (size_t)(k0 + k) * Nn + n0 + nl);
      tile[nl + 0][k] = f2bf(v.x);
      tile[nl + 1][k] = f2bf(v.y);
      tile[nl + 2][k] = f2bf(v.z);
      tile[nl + 3][k] = f2bf(v.w);
    }
  }
  __syncthreads();
  {
    const int kq = (t & 7) * 8, nr = t >> 3;    // 32 n-rows per pass
#pragma unroll
    for (int p = 0; p < 2; p++) {
      const int n = nr + p * 32;
      u16x8 v = *(const u16x8*)&tile[n][kq];
      *(u16x8*)(D + (size_t)(n0 + n) * K + k0 + kq) = v;
    }
  }
}

// ---------------- GEMM1 (bf16, global_load_lds staging) ---------------------
// H[pair] = relu(xb[token] @ w1b[e]^T + b1[e]);  w1b is [H][C] k-contiguous.
__global__ __launch_bounds__(256) void gemm1_async_kernel(
    const unsigned short* __restrict__ xb, const unsigned short* __restrict__ wb,
    const float* __restrict__ b1, const int* __restrict__ counts,
    const int* __restrict__ lists, unsigned short* __restrict__ Hb)
{
  const int e = blockIdx.z;
  int cnt = counts[e]; if (cnt > CAP) cnt = CAP;
  const int m0 = blockIdx.y * BM;
  if (m0 >= cnt) return;
  const int n0 = blockIdx.x * BN;
  const int* list = lists + e * CAP;
  const unsigned short* W = wb + (size_t)e * CDIM * HDIM;

  __shared__ __align__(16) unsigned short As[BM * BK];
  __shared__ __align__(16) unsigned short Bs[BN * BK];

  const int t = threadIdx.x, wid = t >> 6, lane = t & 63;
  // 4 gload issues per matrix per wave; lane's source pre-XOR'd so linear
  // LDS dest (base + lane*16) lands the swizzled layout.
  const char* ag[4]; const char* bg[4];
  unsigned short* al[4]; unsigned short* bl[4];
#pragma unroll
  for (int i = 0; i < 4; i++) {
    const int r = wid * 32 + i * 8 + (lane >> 3);
    const int cb = ((lane & 7) ^ ((r >> 1) & 7)) << 4;  // byte col in row
    int ai = m0 + r; if (ai > cnt - 1) ai = cnt - 1;
    const int tok = list[ai] >> 1;
    ag[i] = (const char*)(xb + (size_t)tok * CDIM) + cb;
    bg[i] = (const char*)(W + (size_t)(n0 + r) * CDIM) + cb;
    al[i] = As + (wid * 32 + i * 8) * BK;   // wave-uniform
    bl[i] = Bs + (wid * 32 + i * 8) * BK;
  }

  const int wm = (wid >> 1) * 64, wn = (wid & 1) * 64;
  const int lrow = lane & 15, lgrp = lane >> 4;
  f32x4 acc[4][4] = {};

  for (int kt = 0; kt < CDIM; kt += BK) {
#pragma unroll
    for (int i = 0; i < 4; i++) {
      gload16(ag[i] + kt * 2, al[i]);
      gload16(bg[i] + kt * 2, bl[i]);
    }
    __syncthreads();
#pragma unroll
    for (int kk = 0; kk < 2; kk++) {
      bf16x8 af[4], bfr[4];
      const int kb = (kk * 32 + lgrp * 8) * 2;
#pragma unroll
      for (int i = 0; i < 4; i++)
        af[i] = *(const bf16x8*)((const char*)As + swz(wm + i * 16 + lrow, kb));
#pragma unroll
      for (int j = 0; j < 4; j++)
        bfr[j] = *(const bf16x8*)((const char*)Bs + swz(wn + j * 16 + lrow, kb));
#pragma unroll
      for (int i = 0; i < 4; i++)
#pragma unroll
        for (int j = 0; j < 4; j++)
          acc[i][j] = __builtin_amdgcn_mfma_f32_16x16x32_bf16(af[i], bfr[j], acc[i][j], 0, 0, 0);
    }
    __syncthreads();
  }

  int hrow[4][4]; bool valid[4][4];
#pragma unroll
  for (int i = 0; i < 4; i++)
#pragma unroll
    for (int r = 0; r < 4; r++) {
      const int mi = m0 + wm + i * 16 + lgrp * 4 + r;
      valid[i][r] = (mi < cnt);
      hrow[i][r] = list[valid[i][r] ? mi : (cnt - 1)];
    }
#pragma unroll
  for (int j = 0; j < 4; j++) {
    const int col = n0 + wn + j * 16 + lrow;
    const float bias = b1[e * HDIM + col];
#pragma unroll
    for (int i = 0; i < 4; i++)
#pragma unroll
      for (int r = 0; r < 4; r++)
        if (valid[i][r]) {
          float h = acc[i][j][r] + bias;
          h = h > 0.f ? h : 0.f;
          Hb[(size_t)hrow[i][r] * HDIM + col] = f2bf(h);
        }
  }
}

// ---------------- GEMM2 (bf16, global_load_lds staging) ---------------------
// out[token] += w_pair * (Hb[pair] @ w2b[e]^T + b2[e]); w2b is [C][H].
__global__ __launch_bounds__(256) void gemm2_async_kernel(
    const unsigned short* __restrict__ Hb, const unsigned short* __restrict__ wb,
    const float* __restrict__ b2, const float* __restrict__ pair_w,
    const int* __restrict__ counts, const int* __restrict__ lists,
    float* __restrict__ out)
{
  const int e = blockIdx.z;
  int cnt = counts[e]; if (cnt > CAP) cnt = CAP;
  const int m0 = blockIdx.y * BM;
  if (m0 >= cnt) return;
  const int n0 = blockIdx.x * BN;
  const int* list = lists + e * CAP;
  const unsigned short* W = wb + (size_t)e * HDIM * CDIM;

  __shared__ __align__(16) unsigned short As[BM * BK];
  __shared__ __align__(16) unsigned short Bs[BN * BK];

  const int t = threadIdx.x, wid = t >> 6, lane = t & 63;
  const char* ag[4]; const char* bg[4];
  unsigned short* al[4]; unsigned short* bl[4];
#pragma unroll
  for (int i = 0; i < 4; i++) {
    const int r = wid * 32 + i * 8 + (lane >> 3);
    const int cb = ((lane & 7) ^ ((r >> 1) & 7)) << 4;
    int ai = m0 + r; if (ai > cnt - 1) ai = cnt - 1;
    const int pr = list[ai];
    ag[i] = (const char*)(Hb + (size_t)pr * HDIM) + cb;
    bg[i] = (const char*)(W + (size_t)(n0 + r) * HDIM) + cb;
    al[i] = As + (wid * 32 + i * 8) * BK;
    bl[i] = Bs + (wid * 32 + i * 8) * BK;
  }

  const int wm = (wid >> 1) * 64, wn = (wid & 1) * 64;
  const int lrow = lane & 15, lgrp = lane >> 4;
  f32x4 acc[4][4] = {};

  for (int kt = 0; kt < HDIM; kt += BK) {
#pragma unroll
    for (int i = 0; i < 4; i++) {
      gload16(ag[i] + kt * 2, al[i]);
      gload16(bg[i] + kt * 2, bl[i]);
    }
    __syncthreads();
#pragma unroll
    for (int kk = 0; kk < 2; kk++) {
      bf16x8 af[4], bfr[4];
      const int kb = (kk * 32 + lgrp * 8) * 2;
#pragma unroll
      for (int i = 0; i < 4; i++)
        af[i] = *(const bf16x8*)((const char*)As + swz(wm + i * 16 + lrow, kb));
#pragma unroll
      for (int j = 0; j < 4; j++)
        bfr[j] = *(const bf16x8*)((const char*)Bs + swz(wn + j * 16 + lrow, kb));
#pragma unroll
      for (int i = 0; i < 4; i++)
#pragma unroll
        for (int j = 0; j < 4; j++)
          acc[i][j] = __builtin_amdgcn_mfma_f32_16x16x32_bf16(af[i], bfr[j], acc[i][j], 0, 0, 0);
    }
    __syncthreads();
  }

  float wgt[4][4]; int tok[4][4]; bool valid[4][4];
#pragma unroll
  for (int i = 0; i < 4; i++)
#pragma unroll
    for (int r = 0; r < 4; r++) {
      const int mi = m0 + wm + i * 16 + lgrp * 4 + r;
      valid[i][r] = (mi < cnt);
      const int p = list[valid[i][r] ? mi : (cnt - 1)];
      wgt[i][r] = pair_w[p];
      tok[i][r] = p >> 1;
    }
#pragma unroll
  for (int j = 0; j < 4; j++) {
    const int col = n0 + wn + j * 16 + lrow;
    const float bias = b2[e * CDIM + col];
#pragma unroll
    for (int i = 0; i < 4; i++)
#pragma unroll
      for (int r = 0; r < 4; r++)
        if (valid[i][r])
          atomicAdd(out + (size_t)tok[i][r] * CDIM + col,
                    wgt[i][r] * (acc[i][j][r] + bias));
  }
}

// ================= round-0 fallback kernels (fp32 inputs, reg-staged) =======
__global__ __launch_bounds__(256) void gemm1_f32_kernel(
    const float* __restrict__ x, const float* __restrict__ w1,
    const float* __restrict__ b1, const int* __restrict__ counts,
    const int* __restrict__ lists, unsigned short* __restrict__ Hb,
    int e_base, int h_by_pair)
{
  const int e = e_base + blockIdx.z;
  int cnt = counts[e]; if (cnt > CAP) cnt = CAP;
  const int m0 = blockIdx.y * BM;
  if (m0 >= cnt) return;
  const int n0 = blockIdx.x * BN;
  const int* list = lists + e * CAP;
  const float* W = w1 + (size_t)e * CDIM * HDIM;
  __shared__ __align__(16) unsigned short As[BM * BK];
  __shared__ __align__(16) unsigned short Bs[BN * BK];
  const int t = threadIdx.x;
  const int a_row = t >> 1, a_half = t & 1;
  int a_idx = m0 + a_row; if (a_idx > cnt - 1) a_idx = cnt - 1;
  const float* a_src = x + (size_t)(list[a_idx] >> 1) * CDIM + a_half * 32;
  const int b_np = t & 63, b_kg = t >> 6;
  const int wid = t >> 6, lane = t & 63;
  const int wm = (wid >> 1) * 64, wn = (wid & 1) * 64;
  const int lrow = lane & 15, lgrp = lane >> 4;
  f32x4 acc[4][4] = {};
  for (int kt = 0; kt < CDIM; kt += BK) {
    {
      const float* s = a_src + kt;
      u16x8 cv[4];
#pragma unroll
      for (int q = 0; q < 4; q++) {
        float4 v0 = *(const float4*)(s + q * 8);
        float4 v1 = *(const float4*)(s + q * 8 + 4);
        cv[q][0] = f2bf(v0.x); cv[q][1] = f2bf(v0.y);
        cv[q][2] = f2bf(v0.z); cv[q][3] = f2bf(v0.w);
        cv[q][4] = f2bf(v1.x); cv[q][5] = f2bf(v1.y);
        cv[q][6] = f2bf(v1.z); cv[q][7] = f2bf(v1.w);
      }
#pragma unroll
      for (int q = 0; q < 4; q++)
        *(u16x8*)((char*)As + swz(a_row, (a_half * 32 + q * 8) * 2)) = cv[q];
    }
    {
#pragma unroll
      for (int it = 0; it < 2; it++) {
        const int k0 = (b_kg + 4 * it) * 8;
        u16x8 c0, c1;
#pragma unroll
        for (int j = 0; j < 8; j++) {
          float2 v = *(const float2*)(W + (size_t)(kt + k0 + j) * HDIM + n0 + 2 * b_np);
          c0[j] = f2bf(v.x); c1[j] = f2bf(v.y);
        }
        *(u16x8*)((char*)Bs + swz(2 * b_np,     k0 * 2)) = c0;
        *(u16x8*)((char*)Bs + swz(2 * b_np + 1, k0 * 2)) = c1;
      }
    }
    __syncthreads();
#pragma unroll
    for (int kk = 0; kk < 2; kk++) {
      bf16x8 af[4], bfr[4];
      const int kb = (kk * 32 + lgrp * 8) * 2;
#pragma unroll
      for (int i = 0; i < 4; i++)
        af[i] = *(const bf16x8*)((const char*)As + swz(wm + i * 16 + lrow, kb));
#pragma unroll
      for (int j = 0; j < 4; j++)
        bfr[j] = *(const bf16x8*)((const char*)Bs + swz(wn + j * 16 + lrow, kb));
#pragma unroll
      for (int i = 0; i < 4; i++)
#pragma unroll
        for (int j = 0; j < 4; j++)
          acc[i][j] = __builtin_amdgcn_mfma_f32_16x16x32_bf16(af[i], bfr[j], acc[i][j], 0, 0, 0);
    }
    __syncthreads();
  }
  int hrow[4][4]; bool valid[4][4];
#pragma unroll
  for (int i = 0; i < 4; i++)
#pragma unroll
    for (int r = 0; r < 4; r++) {
      const int mi = m0 + wm + i * 16 + lgrp * 4 + r;
      valid[i][r] = (mi < cnt);
      const int idx = valid[i][r] ? mi : (cnt - 1);
      hrow[i][r] = h_by_pair ? list[idx] : idx;
    }
#pragma unroll
  for (int j = 0; j < 4; j++) {
    const int col = n0 + wn + j * 16 + lrow;
    const float bias = b1[e * HDIM + col];
#pragma unroll
    for (int i = 0; i < 4; i++)
#pragma unroll
      for (int r = 0; r < 4; r++)
        if (valid[i][r]) {
          float h = acc[i][j][r] + bias;
          h = h > 0.f ? h : 0.f;
          Hb[(size_t)hrow[i][r] * HDIM + col] = f2bf(h);
        }
  }
}

__global__ __launch_bounds__(256) void gemm2_f32_kernel(
    const unsigned short* __restrict__ Hb, const float* __restrict__ w2,
    const float* __restrict__ b2, const float* __restrict__ pair_w,
    const int* __restrict__ counts, const int* __restrict__ lists,
    float* __restrict__ out, int e_base, int h_by_pair)
{
  const int e = e_base + blockIdx.z;
  int cnt = counts[e]; if (cnt > CAP) cnt = CAP;
  const int m0 = blockIdx.y * BM;
  if (m0 >= cnt) return;
  const int n0 = blockIdx.x * BN;
  const int* list = lists + e * CAP;
  const float* W = w2 + (size_t)e * HDIM * CDIM;
  __shared__ __align__(16) unsigned short As[BM * BK];
  __shared__ __align__(16) unsigned short Bs[BN * BK];
  const int t = threadIdx.x;
  const int a_row = t >> 1, a_half = t & 1;
  int a_idx = m0 + a_row; if (a_idx > cnt - 1) a_idx = cnt - 1;
  const unsigned short* a_src =
      Hb + (size_t)(h_by_pair ? list[a_idx] : a_idx) * HDIM + a_half * 32;
  const int b_np = t & 63, b_kg = t >> 6;
  const int wid = t >> 6, lane = t & 63;
  const int wm = (wid >> 1) * 64, wn = (wid & 1) * 64;
  const int lrow = lane & 15, lgrp = lane >> 4;
  f32x4 acc[4][4] = {};
  for (int kt = 0; kt < HDIM; kt += BK) {
    {
      const unsigned short* s = a_src + kt;
#pragma unroll
      for (int q = 0; q < 4; q++) {
        u16x8 v = *(const u16x8*)(s + q * 8);
        *(u16x8*)((char*)As + swz(a_row, (a_half * 32 + q * 8) * 2)) = v;
      }
    }
    {
#pragma unroll
      for (int it = 0; it < 2; it++) {
        const int k0 = (b_kg + 4 * it) * 8;
        u16x8 c0, c1;
#pragma unroll
        for (int j = 0; j < 8; j++) {
          float2 v = *(const float2*)(W + (size_t)(kt + k0 + j) * CDIM + n0 + 2 * b_np);
          c0[j] = f2bf(v.x); c1[j] = f2bf(v.y);
        }
        *(u16x8*)((char*)Bs + swz(2 * b_np,     k0 * 2)) = c0;
        *(u16x8*)((char*)Bs + swz(2 * b_np + 1, k0 * 2)) = c1;
      }
    }
    __syncthreads();
#pragma unroll
    for (int kk = 0; kk < 2; kk++) {
      bf16x8 af[4], bfr[4];
      const int kb = (kk * 32 + lgrp * 8) * 2;
#pragma unroll
      for (int i = 0; i < 4; i++)
        af[i] = *(const bf16x8*)((const char*)As + swz(wm + i * 16 + lrow, kb));
#pragma unroll
      for (int j = 0; j < 4; j++)
        bfr[j] = *(const bf16x8*)((const char*)Bs + swz(wn + j * 16 + lrow, kb));
#pragma unroll
      for (int i = 0; i < 4; i++)
#pragma unroll
        for (int j = 0; j < 4; j++)
          acc[i][j] = __builtin_amdgcn_mfma_f32_16x16x32_bf16(af[i], bfr[j], acc[i][j], 0, 0, 0);
    }
    __syncthreads();
  }
  float wgt[4][4]; int tok[4][4]; bool valid[4][4];
#pragma unroll
  for (int i = 0; i < 4; i++)
#pragma unroll
    for (int r = 0; r < 4; r++) {
      const int mi = m0 + wm + i * 16 + lgrp * 4 + r;
      valid[i][r] = (mi < cnt);
      const int idx = valid[i][r] ? mi : (cnt - 1);
      const int p = list[idx];
      wgt[i][r] = pair_w[p];
      tok[i][r] = p >> 1;
    }
#pragma unroll
  for (int j = 0; j < 4; j++) {
    const int col = n0 + wn + j * 16 + lrow;
    const float bias = b2[e * CDIM + col];
#pragma unroll
    for (int i = 0; i < 4; i++)
#pragma unroll
      for (int r = 0; r < 4; r++)
        if (valid[i][r])
          atomicAdd(out + (size_t)tok[i][r] * CDIM + col,
                    wgt[i][r] * (acc[i][j][r] + bias));
  }
}

extern "C" void kernel_launch(void* const* d_in, const int* in_sizes, int n_in,
                              void* d_out, int out_size, void* d_ws, size_t ws_size,
                              hipStream_t stream)
{
  const float* x  = (const float*)d_in[0];
  const float* wr = (const float*)d_in[1];
  const float* w1 = (const float*)d_in[2];
  const float* b1 = (const float*)d_in[3];
  const float* w2 = (const float*)d_in[4];
  const float* b2 = (const float*)d_in[5];
  float* out = (float*)d_out;

  const int N = in_sizes[0] / CDIM;  // 8192 tokens

  char* ws = (char*)d_ws;
  int* counts = (int*)ws;                                  // 256 B
  int* lists  = (int*)(ws + 256);                          // 16*CAP ints
  float* pw   = (float*)(ws + 256 + NEXP * CAP * 4);       // 2N floats
  size_t off = 256 + (size_t)NEXP * CAP * 4 + (size_t)2 * N * 4;
  off = (off + 255) & ~(size_t)255;
  unsigned short* xb = (unsigned short*)(ws + off);
  const size_t xb_sz = (size_t)N * CDIM * 2;
  unsigned short* Hb = (unsigned short*)(ws + off + xb_sz);
  const size_t Hb_sz = (size_t)2 * N * HDIM * 2;
  unsigned short* wb = (unsigned short*)(ws + off + xb_sz + Hb_sz);
  const size_t wb_sz = (size_t)NEXP * CDIM * HDIM * 2;

  const size_t need_new = off + xb_sz + Hb_sz + wb_sz;     // ~285 MB
  const size_t need_old = off + Hb_sz;                     // ~134.5 MB

  hipMemsetAsync(d_ws, 0, 64, stream);
  hipMemsetAsync(d_out, 0, (size_t)out_size * 4, stream);

  router_kernel<<<N, 64, 0, stream>>>(x, wr, pw, counts, lists);

  if (ws_size >= need_new) {
    cvt_x_kernel<<<(N * CDIM / 8 + 255) / 256, 256, 0, stream>>>(
        x, xb, N * CDIM / 8);
    // w1 [C][H] -> wb [H][C]
    transpose_cvt_kernel<<<dim3(HDIM / 64, CDIM / 64, NEXP), 256, 0, stream>>>(
        w1, wb, CDIM, HDIM);
    gemm1_async_kernel<<<dim3(HDIM / BN, CAP / BM, NEXP), 256, 0, stream>>>(
        xb, wb, b1, counts, lists, Hb);
    // w2 [H][C] -> wb [C][H]  (reuses wb; stream-ordered after gemm1)
    transpose_cvt_kernel<<<dim3(CDIM / 64, HDIM / 64, NEXP), 256, 0, stream>>>(
        w2, wb, HDIM, CDIM);
    gemm2_async_kernel<<<dim3(CDIM / BN, CAP / BM, NEXP), 256, 0, stream>>>(
        Hb, wb, b2, pw, counts, lists, out);
  } else if (ws_size >= need_old) {
    unsigned short* Hb0 = (unsigned short*)(ws + off);  // old layout
    gemm1_f32_kernel<<<dim3(HDIM / BN, CAP / BM, NEXP), 256, 0, stream>>>(
        x, w1, b1, counts, lists, Hb0, 0, 1);
    gemm2_f32_kernel<<<dim3(CDIM / BN, CAP / BM, NEXP), 256, 0, stream>>>(
        Hb0, w2, b2, pw, counts, lists, out, 0, 1);
  }
}